// Round 14
// baseline (4986.798 us; speedup 1.0000x reference)
//
#include <hip/hip_runtime.h>
#include <math.h>

// Problem constants (fixed by reference file)
#define NB   512    // N = batch of user pairs
#define MM   254    // M uav nodes
#define SS   256    // S = M + 2 graph nodes per b
#define HH   128    // H hidden
#define RTOT 1278   // 2N + M rows in `outputs`
#define NBLK 256    // decode blocks; each handles b and b+256

#define C2   2.885390081777927f   // 2*log2(e): tanh arg pre-scale
#define C1   1.442695040888963f   // log2(e)

__device__ __forceinline__ float rcpf(float x)  { return __builtin_amdgcn_rcpf(x); }
__device__ __forceinline__ float exp2f_(float x){ return __builtin_amdgcn_exp2f(x); }
__device__ __forceinline__ float sigm2(float x) { return rcpf(1.0f + exp2f_(-C1 * x)); }
__device__ __forceinline__ float tanh2(float x) { return 1.0f - 2.0f * rcpf(1.0f + exp2f_(C2 * x)); }

__device__ __forceinline__ float4 fma4(float s, float4 w, float4 a) {
  a.x = fmaf(s, w.x, a.x); a.y = fmaf(s, w.y, a.y);
  a.z = fmaf(s, w.z, a.z); a.w = fmaf(s, w.w, a.w);
  return a;
}

// Per node row r: e = pos @ W_embed + b_embed (128),
//   EWiP[r][j]  = float4(i,f,g,o) columns of e@lstm_Wi + lstm_b (bias folded)
//   W1eQ[h4][r] = float4 of C2*W1e[4h4..4h4+3]  (pre-scaled, coalesced over r)
__global__ __launch_bounds__(128) void precompute_k(
    const float* __restrict__ outputs, const float* __restrict__ Wemb,
    const float* __restrict__ bemb, const float* __restrict__ Wi,
    const float* __restrict__ W1, const float* __restrict__ lb,
    float4* __restrict__ EWiP, float4* __restrict__ W1eQ)
{
  int r = blockIdx.x;
  int t = threadIdx.x;  // 128
  __shared__ float e[HH];
  __shared__ float w1e[HH];
  float px = outputs[2 * r], py = outputs[2 * r + 1];
  e[t] = px * Wemb[t] + py * Wemb[HH + t] + bemb[t];
  __syncthreads();
  float acc = 0.f;
#pragma unroll 8
  for (int h = 0; h < HH; ++h) acc = fmaf(e[h], W1[h * HH + t], acc);
  w1e[t] = acc;
  float g4[4];
#pragma unroll
  for (int c = 0; c < 4; ++c) {
    int j = t + c * HH;
    float a = 0.f;
#pragma unroll 8
    for (int h = 0; h < HH; ++h) a = fmaf(e[h], Wi[h * 512 + j], a);
    g4[c] = a + lb[j];
  }
  float4 v4; v4.x = g4[0]; v4.y = g4[1]; v4.z = g4[2]; v4.w = g4[3];
  EWiP[(size_t)r * HH + t] = v4;
  __syncthreads();
  if (t < 32) {
    float4 p;
    p.x = C2 * w1e[4 * t];     p.y = C2 * w1e[4 * t + 1];
    p.z = C2 * w1e[4 * t + 2]; p.w = C2 * w1e[4 * t + 3];
    W1eQ[(size_t)t * RTOT + r] = p;
  }
}

// W2T[128][128] = W2^T
__global__ __launch_bounds__(128) void transpose_k(
    const float* __restrict__ W2, float* __restrict__ W2T)
{
  int j = blockIdx.x, k = threadIdx.x;
  W2T[(size_t)j * 128 + k] = W2[(size_t)k * 128 + j];
}

// One block per TWO batch elements. 1024 threads = two 8-wave TEAMS.
// Team 0 runs b=bid, team 1 runs b=bid+256, offset 2 pipeline stages behind
// in the same barrier stream: every barrier interval pairs a fat phase of
// one team with a thin/latency phase of the other (A,E)(B,F)(C,A)(E,B)(F,C),
// filling the SIMDs that lockstep phases left idle.
__global__ __launch_bounds__(1024) void decode_k(
    const float* __restrict__ outputs, const float* __restrict__ Wh,
    const float* __restrict__ W2T, const float* __restrict__ av,
    const float4* __restrict__ EWiP, const float4* __restrict__ W1eQ,
    float* __restrict__ maxd_out)
{
  const int t = threadIdx.x;       // 0..1023
  const int bid = blockIdx.x;
  const int team  = t >> 9;        // 0/1
  const int local = t & 511;       // index within team
  const int g = team;

  __shared__ float WhL[64][512];            // 128 KB: Wh rows 64..127
  __shared__ float posU[2 * MM];            // uav node positions
  __shared__ float dstS[2][2];
  __shared__ __align__(16) float hS[2][HH];
  __shared__ __align__(16) float qS[2][HH]; // pre-scaled by C2
  __shared__ __align__(16) float vS2[HH];   // -2*av
  __shared__ float sumvS[2];
  __shared__ __align__(16) float pS[2][4][512]; // gates partials [g][kq][j] 16KB
  __shared__ float lp[2][2][SS];            // logit partials [g][hhalf][u]
  __shared__ int   lsS[2][SS];
  __shared__ int   actS[2][254];
  __shared__ int   cntS[2], curS[2];

  // ---- init (all 1024 threads) ----
  for (int i = t; i < 64 * 512; i += 1024) ((float*)WhL)[i] = Wh[64 * 512 + i];
  for (int i = t; i < 2 * MM; i += 1024)   posU[i] = outputs[4 * NB + i];
  if (t < 256) { int gg = t >> 7, j = t & 127; hS[gg][j] = 0.f; }
  if (t < HH) vS2[t] = -2.0f * av[t];
  if (t >= 256 && t < 258) {
    int half = t - 256; float s = 0.f;
    for (int h = half * 64; h < half * 64 + 64; ++h) s += av[h];
    sumvS[half] = s;
  }
  if (t < 254) actS[0][t] = t + 1;
  else if (t >= 512 && t < 766) actS[1][t - 512] = t - 511;
  if (t == 0) {
    cntS[0] = 254; curS[0] = bid;
    dstS[0][0] = outputs[2 * (NB + bid)]; dstS[0][1] = outputs[2 * (NB + bid) + 1];
  }
  if (t == 512) {
    cntS[1] = 254; curS[1] = bid + NBLK;
    dstS[1][0] = outputs[2 * (NB + bid + NBLK)];
    dstS[1][1] = outputs[2 * (NB + bid + NBLK) + 1];
  }
  __syncthreads();

  float px = 0.f, py = 0.f, md = 0.f;       // live in local==0 of each team
  if (local == 0) {
    int b = bid + (g << 8);
    px = outputs[2 * b]; py = outputs[2 * b + 1];
  }

  float creg = 0.f;                          // c-state, owned by local<128
  float4 ew4 = make_float4(0.f, 0.f, 0.f, 0.f);  // A->B carried prefetch

  // pipeline position: team0 starts at phase 0, team1 two stages behind
  int ph = (team == 0) ? 0 : -2;
  int lk = 0;

  const int jq  = local & 127;       // A: float4 column group (j = 4*jq..)
  const int kq  = local >> 7;        // A: k-quarter 0..3
  const int cj  = (local >> 2) & 127;// C: q column
  const int ckq = local & 3;         // C: k-quarter
  const int lhf = local >> 8;        // E: h-half
  const int lu  = local & 255;       // E: node slot

  const int NSTAGE = 5 * SS + 2;
  for (int sg = 0; sg < NSTAGE; ++sg) {
    bool valid = (ph >= 0) && (lk < SS);
    if (valid) {
      if (ph == 0) {
        // ---- A: gates partials pS[g][kq][j] = sum_{k in quarter} h[k]*Wh[k][j]
        if (local < 128) ew4 = EWiP[(size_t)curS[g] * HH + local];
        float4 acc = make_float4(0.f, 0.f, 0.f, 0.f);
        if (kq < 2) {
          // global half: rows k = kq*32 + [0,32) of Wh, float4 over j
          const float4* wg = (const float4*)(Wh + (size_t)(kq * 32) * 512) + jq;
          const float4* h4 = (const float4*)(&hS[g][kq * 32]);
          float4 wb[8];
#pragma unroll
          for (int b = 0; b < 4; ++b) {
#pragma unroll
            for (int i = 0; i < 8; ++i) wb[i] = wg[(size_t)(b * 8 + i) * 128];
#pragma unroll
            for (int i2 = 0; i2 < 2; ++i2) {
              float4 h = h4[b * 2 + i2];
              acc = fma4(h.x, wb[i2 * 4 + 0], acc);
              acc = fma4(h.y, wb[i2 * 4 + 1], acc);
              acc = fma4(h.z, wb[i2 * 4 + 2], acc);
              acc = fma4(h.w, wb[i2 * 4 + 3], acc);
            }
          }
        } else {
          // LDS half: rows k = kq*32 + [0,32) (WhL row k-64), b128 conflict-free
          const float4* wl = (const float4*)(&WhL[(kq - 2) * 32][0]) + jq;
          const float4* h4 = (const float4*)(&hS[g][kq * 32]);
#pragma unroll
          for (int i = 0; i < 8; ++i) {
            float4 h  = h4[i];
            float4 w0 = wl[(size_t)(4 * i + 0) * 128];
            float4 w1 = wl[(size_t)(4 * i + 1) * 128];
            float4 w2 = wl[(size_t)(4 * i + 2) * 128];
            float4 w3 = wl[(size_t)(4 * i + 3) * 128];
            acc = fma4(h.x, w0, acc);
            acc = fma4(h.y, w1, acc);
            acc = fma4(h.z, w2, acc);
            acc = fma4(h.w, w3, acc);
          }
        }
        *(float4*)&pS[g][kq][4 * jq] = acc;
      } else if (ph == 1) {
        // ---- B: LSTM cell (local<128; order i,f,g,o)
        if (local < 128) {
          int jj = local;
          float ei = ew4.x + ((pS[g][0][jj]       + pS[g][1][jj])       + (pS[g][2][jj]       + pS[g][3][jj]));
          float ef = ew4.y + ((pS[g][0][128 + jj] + pS[g][1][128 + jj]) + (pS[g][2][128 + jj] + pS[g][3][128 + jj]));
          float eg = ew4.z + ((pS[g][0][256 + jj] + pS[g][1][256 + jj]) + (pS[g][2][256 + jj] + pS[g][3][256 + jj]));
          float eo = ew4.w + ((pS[g][0][384 + jj] + pS[g][1][384 + jj]) + (pS[g][2][384 + jj] + pS[g][3][384 + jj]));
          float iv = sigm2(ei), fv = sigm2(ef), gv = tanh2(eg), ov = sigm2(eo);
          float cn = fv * creg + iv * gv;
          creg = cn;
          hS[g][jj] = ov * tanh2(cn);
        }
      } else if (ph == 2) {
        // ---- C: q partials, quad k-split + shfl reduce
        const float4* w4 = (const float4*)(W2T + (size_t)cj * 128 + ckq * 32);
        const float4* h4 = (const float4*)(&hS[g][ckq * 32]);
        float p0 = 0.f, p1 = 0.f;
#pragma unroll
        for (int i = 0; i < 8; ++i) {
          float4 w = w4[i], h = h4[i];
          p0 = fmaf(h.x, w.x, p0); p1 = fmaf(h.y, w.y, p1);
          p0 = fmaf(h.z, w.z, p0); p1 = fmaf(h.w, w.w, p1);
        }
        float p = p0 + p1;
        p += __shfl_xor(p, 1);
        p += __shfl_xor(p, 2);
        if (ckq == 0) qS[g][cj] = C2 * p;   // pre-scaled for exp2
      } else if (ph == 3) {
        // ---- E: logits over active nodes (fused tanh, div-free)
        int cnt = cntS[g];
        int cntEff = cnt + (lk > 0 ? 1 : 0);
        if (lu < cntEff) {
          int s = (lu == cnt) ? 255 : actS[g][lu];
          int r = (s == 255) ? (NB + bid + (g << 8)) : (2 * NB + s - 1);
          const float4* wp = W1eQ + (size_t)(lhf * 16) * RTOT + r;
          const float4* qv4 = (const float4*)(&qS[g][lhf * 64]);
          const float4* vv4 = (const float4*)(&vS2[lhf * 64]);
          float c0 = 0.f, c1 = 0.f;
#pragma unroll 4
          for (int i = 0; i < 16; ++i) {
            float4 w = wp[(size_t)i * RTOT];
            float4 q = qv4[i];
            float4 v = vv4[i];
            c0 = fmaf(v.x, rcpf(1.0f + exp2f_(w.x + q.x)), c0);
            c1 = fmaf(v.y, rcpf(1.0f + exp2f_(w.y + q.y)), c1);
            c0 = fmaf(v.z, rcpf(1.0f + exp2f_(w.z + q.z)), c0);
            c1 = fmaf(v.w, rcpf(1.0f + exp2f_(w.w + q.w)), c1);
          }
          lp[g][lhf][lu] = (c0 + c1) + sumvS[lhf];
          if (lhf == 0) lsS[g][lu] = s;
        }
      } else {
        // ---- F: argmax + state update (wave 0 of team)
        if (local < 64) {
          int lane = local;
          int cnt = cntS[g];
          int cntEff = cnt + (lk > 0 ? 1 : 0);
          float val = -INFINITY;
          unsigned key = 0xFFFFFFFFu;
#pragma unroll
          for (int c = 0; c < 4; ++c) {
            int u = lane + 64 * c;
            if (u < cntEff) {
              float v2 = lp[g][0][u] + lp[g][1][u];
              unsigned k2 = ((unsigned)lsS[g][u] << 16) | (unsigned)u;
              if (v2 > val || (v2 == val && k2 < key)) { val = v2; key = k2; }
            }
          }
#pragma unroll
          for (int off = 1; off < 64; off <<= 1) {
            float v2 = __shfl_xor(val, off);
            unsigned k2 = __shfl_xor(key, off);
            if (v2 > val || (v2 == val && k2 < key)) { val = v2; key = k2; }
          }
          if (lane == 0) {
            int s   = (int)(key >> 16);
            int pos = (int)(key & 0xFFFFu);
            int rn  = (s == 255) ? (NB + bid + (g << 8)) : (2 * NB + s - 1);
            float nx, ny;
            if (s == 255) { nx = dstS[g][0]; ny = dstS[g][1]; }
            else          { nx = posU[2 * (s - 1)]; ny = posU[2 * (s - 1) + 1]; }
            float dx = nx - px, dy = ny - py;
            float d = sqrtf(dx * dx + dy * dy + 1e-12f);
            if (d > md) md = d;
            px = nx; py = ny;
            curS[g] = rn;
            if (s != 255) { actS[g][pos] = actS[g][cnt - 1]; cntS[g] = cnt - 1; }
          }
        }
      }
    }
    // advance this team's pipeline position
    ++ph;
    if (ph == 5) { ph = 0; ++lk; }
    __syncthreads();
  }

  if (local == 0) maxd_out[bid + (g << 8)] = md;
}

__global__ __launch_bounds__(512) void reduce_k(const float* __restrict__ maxd,
                                               float* __restrict__ out)
{
  __shared__ float s[512];
  int t = threadIdx.x;
  s[t] = maxd[t];
  __syncthreads();
  for (int off = 256; off > 0; off >>= 1) {
    if (t < off) s[t] += s[t + off];
    __syncthreads();
  }
  if (t == 0) out[0] = s[0] * (1.0f / 512.0f);
}

extern "C" void kernel_launch(void* const* d_in, const int* in_sizes, int n_in,
                              void* d_out, int out_size, void* d_ws, size_t ws_size,
                              hipStream_t stream) {
  const float* outputs = (const float*)d_in[0];
  const float* Wemb    = (const float*)d_in[1];
  const float* bemb    = (const float*)d_in[2];
  const float* Wi      = (const float*)d_in[3];
  const float* Wh      = (const float*)d_in[4];
  const float* lb      = (const float*)d_in[5];
  const float* W1      = (const float*)d_in[6];
  const float* W2      = (const float*)d_in[7];
  const float* av      = (const float*)d_in[8];
  // d_in[9] = N (known constant 512)

  float* ws    = (float*)d_ws;
  float4* EWiP = (float4*)ws;                               // RTOT*128 float4
  float4* W1eQ = (float4*)(ws + (size_t)RTOT * 512);        // RTOT*32 float4
  float*  W2T  = ws + (size_t)RTOT * 512 + (size_t)RTOT * 128;   // 128*128
  float*  maxd = W2T + (size_t)128 * 128;                   // 512

  hipLaunchKernelGGL(transpose_k, dim3(128), dim3(128), 0, stream, W2, W2T);
  hipLaunchKernelGGL(precompute_k, dim3(RTOT), dim3(HH), 0, stream,
                     outputs, Wemb, bemb, Wi, W1, lb, EWiP, W1eQ);
  hipLaunchKernelGGL(decode_k, dim3(NBLK), dim3(1024), 0, stream,
                     outputs, Wh, W2T, av, EWiP, W1eQ, maxd);
  hipLaunchKernelGGL(reduce_k, dim3(1), dim3(512), 0, stream, maxd, (float*)d_out);
}

// Round 15
// 2121.309 us; speedup vs baseline: 2.3508x; 2.3508x over previous
//
#include <hip/hip_runtime.h>
#include <math.h>

// Problem constants (fixed by reference file)
#define NB   512    // N = batch of user pairs
#define MM   254    // M uav nodes
#define SS   256    // S = M + 2 graph nodes per b
#define HH   128    // H hidden
#define RTOT 1278   // 2N + M rows in `outputs`
#define NBLK 256    // decode blocks; each handles b and b+256

#define C2   2.885390081777927f   // 2*log2(e): tanh arg pre-scale
#define C1   1.442695040888963f   // log2(e)

__device__ __forceinline__ float rcpf(float x)  { return __builtin_amdgcn_rcpf(x); }
__device__ __forceinline__ float exp2f_(float x){ return __builtin_amdgcn_exp2f(x); }
__device__ __forceinline__ float sigm2(float x) { return rcpf(1.0f + exp2f_(-C1 * x)); }
__device__ __forceinline__ float tanh2(float x) { return 1.0f - 2.0f * rcpf(1.0f + exp2f_(C2 * x)); }

// pos is 2-D, so e = pos@Wemb+bemb is rank-2 in (px,py); therefore
//   EWi[r][j] = px*Ai[j] + py*Bi[j] + Ci[j]          (Ci includes lstm_b)
//   C2*W1e[r][h] = px*A1s[h] + py*B1s[h] + C1s[h]    (pre-scaled by C2)
// coef layout: Ai[512] Bi[512] Ci[512] A1s[128] B1s[128] C1s[128]
__global__ __launch_bounds__(512) void coef_k(
    const float* __restrict__ Wemb, const float* __restrict__ bemb,
    const float* __restrict__ Wi, const float* __restrict__ W1,
    const float* __restrict__ lb, float* __restrict__ coef)
{
  int j = threadIdx.x;  // 0..511
  float a = 0.f, b = 0.f, c = 0.f;
#pragma unroll 8
  for (int h = 0; h < HH; ++h) {
    float w = Wi[(size_t)h * 512 + j];
    a = fmaf(Wemb[h], w, a);
    b = fmaf(Wemb[HH + h], w, b);
    c = fmaf(bemb[h], w, c);
  }
  coef[j] = a; coef[512 + j] = b; coef[1024 + j] = c + lb[j];
  if (j < HH) {
    float a1 = 0.f, b1 = 0.f, c1 = 0.f;
#pragma unroll 8
    for (int h = 0; h < HH; ++h) {
      float w = W1[(size_t)h * HH + j];
      a1 = fmaf(Wemb[h], w, a1);
      b1 = fmaf(Wemb[HH + h], w, b1);
      c1 = fmaf(bemb[h], w, c1);
    }
    coef[1536 + j] = C2 * a1; coef[1664 + j] = C2 * b1; coef[1792 + j] = C2 * c1;
  }
}

// WhT[512][128] = Wh^T, W2T[128][128] = W2^T (per-thread-row float4 reads)
__global__ __launch_bounds__(128) void transpose_k(
    const float* __restrict__ Wh, const float* __restrict__ W2,
    float* __restrict__ WhT, float* __restrict__ W2T)
{
  int bidx = blockIdx.x;  // 0..639
  int k = threadIdx.x;    // 0..127
  if (bidx < 512) WhT[(size_t)bidx * 128 + k] = Wh[(size_t)k * 512 + bidx];
  else {
    int j = bidx - 512;
    W2T[(size_t)j * 128 + k] = W2[(size_t)k * 128 + j];
  }
}

// One block per TWO batch elements (b, b+256). 1024 threads, grid 256.
// ~159 KB LDS -> 1 block/CU (4 waves/EU) -> 128-VGPR budget (whreg resident).
// Rank-2 coefficient vectors replace the EWi/W1e tables: phases B and E have
// ZERO global loads; L2 working set shrinks to Wh+W2T (~320 KB).
__global__ __attribute__((amdgpu_waves_per_eu(4, 4)))
__launch_bounds__(1024) void decode_k(
    const float* __restrict__ outputs, const float* __restrict__ WhT,
    const float* __restrict__ Wh, const float* __restrict__ W2T,
    const float* __restrict__ av, const float* __restrict__ coef,
    float* __restrict__ maxd_out)
{
  const int t = threadIdx.x;   // 0..1023
  const int bid = blockIdx.x;

  __shared__ float WhL[64][512];            // 128 KB: Wh rows 64..127
  __shared__ float posU[2 * MM];            // uav node positions
  __shared__ float dstS[2][2];              // per-g dst node position
  __shared__ float curP[2][2];              // per-g current node position
  __shared__ __align__(16) float hS[2][HH];
  __shared__ __align__(16) float qC[2][HH]; // C2*q + C1s
  __shared__ __align__(16) float vS2[HH];   // -2*av
  __shared__ float sumvS[2];                // per-half sum of av
  __shared__ __align__(16) float AiS[512], BiS[512], CiS[512];
  __shared__ __align__(16) float A1sS[HH], B1sS[HH], C1sS[HH];
  __shared__ float pS[2][2][512];           // gates partials [g][gh][j]
  __shared__ float lp[2][2][SS];            // logit partials [g][hhalf][u]
  __shared__ int   lsS[2][SS];
  __shared__ int   actS[2][254];
  __shared__ int   cntS[2];

  // Bank-conflict-free gates mapping: within each 32-lane group gh is
  // uniform and gj covers 32 consecutive values (banks 0..31 distinct).
  const int gh  = (t >> 5) & 1;            // gates k-half (0/1)
  const int gj  = ((t >> 6) << 5) | (t & 31);  // gates column, 0..511
  const int cg  = t >> 9;        // q batch slot
  const int cj  = (t >> 2) & 127;// q column
  const int ckq = t & 3;         // q k-quarter
  const int lg  = t >> 9;        // logits batch slot
  const int lhf = (t >> 8) & 1;  // logits h-half
  const int lu  = t & 255;       // logits node slot

  // ---- persistent register-resident Wh global half (k in gh*32+[0,32)) ----
  float4 whreg[8];
  {
    const float4* wg4 = (const float4*)(WhT + (size_t)gj * 128 + gh * 32);
#pragma unroll
    for (int i = 0; i < 8; ++i) whreg[i] = wg4[i];
  }

  // ---- init ----
  for (int i = t; i < 64 * 512; i += 1024) ((float*)WhL)[i] = Wh[64 * 512 + i];
  for (int i = t; i < 2 * MM; i += 1024)   posU[i] = outputs[4 * NB + i];
  if (t < 512) { AiS[t] = coef[t]; BiS[t] = coef[512 + t]; CiS[t] = coef[1024 + t]; }
  if (t < HH)  { A1sS[t] = coef[1536 + t]; B1sS[t] = coef[1664 + t]; C1sS[t] = coef[1792 + t]; }
  if (t < 256) { int gg = t >> 7, j = t & 127; hS[gg][j] = 0.f; }
  if (t < HH) vS2[t] = -2.0f * av[t];
  if (t >= 256 && t < 258) {
    int half = t - 256; float s = 0.f;
    for (int h = half * 64; h < half * 64 + 64; ++h) s += av[h];
    sumvS[half] = s;
  }
  if (t < 254) actS[0][t] = t + 1;
  else if (t >= 512 && t < 766) actS[1][t - 512] = t - 511;
  if (t == 0) {
    cntS[0] = 254;
    dstS[0][0] = outputs[2 * (NB + bid)]; dstS[0][1] = outputs[2 * (NB + bid) + 1];
    curP[0][0] = outputs[2 * bid];        curP[0][1] = outputs[2 * bid + 1];
  }
  if (t == 512) {
    cntS[1] = 254;
    dstS[1][0] = outputs[2 * (NB + bid + NBLK)];
    dstS[1][1] = outputs[2 * (NB + bid + NBLK) + 1];
    curP[1][0] = outputs[2 * (bid + NBLK)];
    curP[1][1] = outputs[2 * (bid + NBLK) + 1];
  }
  __syncthreads();

  float px = 0.f, py = 0.f, md = 0.f;   // live in t==0 (g0) and t==512 (g1)
  if (t == 0)   { px = curP[0][0]; py = curP[0][1]; }
  if (t == 512) { px = curP[1][0]; py = curP[1][1]; }

  float creg = 0.f;                     // LSTM c-state, owned by t<256

  for (int k = 0; k < SS; ++k) {
    // ---- Phase A: gates partials. k in gh*32+[0,32) from whreg,
    // k in 64+gh*32+[0,32) from WhL (conflict-free). Both g per thread.
    {
      float a0G = 0.f, a1G = 0.f, a0L = 0.f, a1L = 0.f;
      {
        const float* wl = &WhL[gh * 32][gj];
        const float4* hb0 = (const float4*)(&hS[0][64 + gh * 32]);
        const float4* hb1 = (const float4*)(&hS[1][64 + gh * 32]);
#pragma unroll
        for (int i = 0; i < 8; ++i) {                     // LDS half
          float4 h0 = hb0[i], h1 = hb1[i];
          float wa = wl[(size_t)(4 * i) * 512];
          float wbv = wl[(size_t)(4 * i + 1) * 512];
          float wc = wl[(size_t)(4 * i + 2) * 512];
          float wd = wl[(size_t)(4 * i + 3) * 512];
          a0L = fmaf(h0.x, wa, a0L); a0L = fmaf(h0.y, wbv, a0L);
          a0L = fmaf(h0.z, wc, a0L); a0L = fmaf(h0.w, wd, a0L);
          a1L = fmaf(h1.x, wa, a1L); a1L = fmaf(h1.y, wbv, a1L);
          a1L = fmaf(h1.z, wc, a1L); a1L = fmaf(h1.w, wd, a1L);
        }
      }
      {
        const float4* hb0 = (const float4*)(&hS[0][gh * 32]);
        const float4* hb1 = (const float4*)(&hS[1][gh * 32]);
#pragma unroll
        for (int i = 0; i < 8; ++i) {                     // register half
          float4 h0 = hb0[i], h1 = hb1[i];
          float4 w = whreg[i];
          a0G = fmaf(h0.x, w.x, a0G); a0G = fmaf(h0.y, w.y, a0G);
          a0G = fmaf(h0.z, w.z, a0G); a0G = fmaf(h0.w, w.w, a0G);
          a1G = fmaf(h1.x, w.x, a1G); a1G = fmaf(h1.y, w.y, a1G);
          a1G = fmaf(h1.z, w.z, a1G); a1G = fmaf(h1.w, w.w, a1G);
        }
      }
      pS[0][gh][gj] = a0G + a0L;
      pS[1][gh][gj] = a1G + a1L;
    }
    __syncthreads();  // B1

    // ---- Phase B: LSTM cell (t<256; order i,f,g,o); EWi from rank-2 coef
    if (t < 256) {
      int g = t >> 7, jj = t & 127;
      float pxc = curP[g][0], pyc = curP[g][1];
      float ei = fmaf(pxc, AiS[jj],       fmaf(pyc, BiS[jj],       CiS[jj]))       + (pS[g][0][jj]       + pS[g][1][jj]);
      float ef = fmaf(pxc, AiS[128 + jj], fmaf(pyc, BiS[128 + jj], CiS[128 + jj])) + (pS[g][0][128 + jj] + pS[g][1][128 + jj]);
      float eg = fmaf(pxc, AiS[256 + jj], fmaf(pyc, BiS[256 + jj], CiS[256 + jj])) + (pS[g][0][256 + jj] + pS[g][1][256 + jj]);
      float eo = fmaf(pxc, AiS[384 + jj], fmaf(pyc, BiS[384 + jj], CiS[384 + jj])) + (pS[g][0][384 + jj] + pS[g][1][384 + jj]);
      float iv = sigm2(ei), fv = sigm2(ef), gv = tanh2(eg), ov = sigm2(eo);
      float cn = fv * creg + iv * gv;
      creg = cn;
      hS[g][jj] = ov * tanh2(cn);
    }
    __syncthreads();  // B2

    // ---- Phase C: q[g][j], quad k-split + shfl reduce; fold C1s in
    {
      const float4* w4 = (const float4*)(W2T + (size_t)cj * 128 + ckq * 32);
      const float4* h4 = (const float4*)(&hS[cg][ckq * 32]);
      float p0 = 0.f, p1 = 0.f;
#pragma unroll
      for (int i = 0; i < 8; ++i) {
        float4 w = w4[i], h = h4[i];
        p0 = fmaf(h.x, w.x, p0); p1 = fmaf(h.y, w.y, p1);
        p0 = fmaf(h.z, w.z, p0); p1 = fmaf(h.w, w.w, p1);
      }
      float p = p0 + p1;
      p += __shfl_xor(p, 1);
      p += __shfl_xor(p, 2);
      if (ckq == 0) qC[cg][cj] = fmaf(C2, p, C1sS[cj]);
    }
    __syncthreads();  // B3

    // ---- Phase E: logits; arg = px*A1s + py*B1s + (C2*q + C1s) — pure LDS
    {
      int cnt = cntS[lg];
      int cntEff = cnt + (k > 0 ? 1 : 0);   // dst node re-enters for k>0
      if (lu < cntEff) {
        int s = (lu == cnt) ? 255 : actS[lg][lu];
        float pxn, pyn;
        if (s == 255) { pxn = dstS[lg][0]; pyn = dstS[lg][1]; }
        else          { pxn = posU[2 * (s - 1)]; pyn = posU[2 * (s - 1) + 1]; }
        const float4* a14 = (const float4*)(&A1sS[lhf * 64]);
        const float4* b14 = (const float4*)(&B1sS[lhf * 64]);
        const float4* qc4 = (const float4*)(&qC[lg][lhf * 64]);
        const float4* vv4 = (const float4*)(&vS2[lhf * 64]);
        float c0 = 0.f, c1 = 0.f;
#pragma unroll 4
        for (int i = 0; i < 16; ++i) {
          float4 a = a14[i], b = b14[i], qc = qc4[i], v = vv4[i];
          float wx = fmaf(pxn, a.x, fmaf(pyn, b.x, qc.x));
          float wy = fmaf(pxn, a.y, fmaf(pyn, b.y, qc.y));
          float wz = fmaf(pxn, a.z, fmaf(pyn, b.z, qc.z));
          float ww = fmaf(pxn, a.w, fmaf(pyn, b.w, qc.w));
          c0 = fmaf(v.x, rcpf(1.0f + exp2f_(wx)), c0);
          c1 = fmaf(v.y, rcpf(1.0f + exp2f_(wy)), c1);
          c0 = fmaf(v.z, rcpf(1.0f + exp2f_(wz)), c0);
          c1 = fmaf(v.w, rcpf(1.0f + exp2f_(ww)), c1);
        }
        lp[lg][lhf][lu] = (c0 + c1) + sumvS[lhf];
        if (lhf == 0) lsS[lg][lu] = s;
      }
    }
    __syncthreads();  // B4

    // ---- Phase F: argmax + state update (wave 0 -> g0, wave 8 -> g1)
    if ((t < 64) || (t >= 512 && t < 576)) {
      int g = t >> 9;
      int lane = t & 63;
      int cnt = cntS[g];
      int cntEff = cnt + (k > 0 ? 1 : 0);
      float val = -INFINITY;
      unsigned key = 0xFFFFFFFFu;
#pragma unroll
      for (int c = 0; c < 4; ++c) {
        int u = lane + 64 * c;
        if (u < cntEff) {
          float v2 = lp[g][0][u] + lp[g][1][u];
          unsigned k2 = ((unsigned)lsS[g][u] << 16) | (unsigned)u;
          if (v2 > val || (v2 == val && k2 < key)) { val = v2; key = k2; }
        }
      }
#pragma unroll
      for (int off = 1; off < 64; off <<= 1) {
        float v2 = __shfl_xor(val, off);
        unsigned k2 = __shfl_xor(key, off);
        if (v2 > val || (v2 == val && k2 < key)) { val = v2; key = k2; }
      }
      if (lane == 0) {
        int s   = (int)(key >> 16);
        int pos = (int)(key & 0xFFFFu);
        float nx, ny;
        if (s == 255) { nx = dstS[g][0]; ny = dstS[g][1]; }
        else          { nx = posU[2 * (s - 1)]; ny = posU[2 * (s - 1) + 1]; }
        float dx = nx - px, dy = ny - py;
        float d = sqrtf(dx * dx + dy * dy + 1e-12f);
        if (d > md) md = d;
        px = nx; py = ny;
        curP[g][0] = nx; curP[g][1] = ny;
        if (s != 255) { actS[g][pos] = actS[g][cnt - 1]; cntS[g] = cnt - 1; }
      }
    }
    __syncthreads();  // B5
  }

  if (t == 0)   maxd_out[bid] = md;
  if (t == 512) maxd_out[bid + NBLK] = md;
}

__global__ __launch_bounds__(512) void reduce_k(const float* __restrict__ maxd,
                                               float* __restrict__ out)
{
  __shared__ float s[512];
  int t = threadIdx.x;
  s[t] = maxd[t];
  __syncthreads();
  for (int off = 256; off > 0; off >>= 1) {
    if (t < off) s[t] += s[t + off];
    __syncthreads();
  }
  if (t == 0) out[0] = s[0] * (1.0f / 512.0f);
}

extern "C" void kernel_launch(void* const* d_in, const int* in_sizes, int n_in,
                              void* d_out, int out_size, void* d_ws, size_t ws_size,
                              hipStream_t stream) {
  const float* outputs = (const float*)d_in[0];
  const float* Wemb    = (const float*)d_in[1];
  const float* bemb    = (const float*)d_in[2];
  const float* Wi      = (const float*)d_in[3];
  const float* Wh      = (const float*)d_in[4];
  const float* lb      = (const float*)d_in[5];
  const float* W1      = (const float*)d_in[6];
  const float* W2      = (const float*)d_in[7];
  const float* av      = (const float*)d_in[8];
  // d_in[9] = N (known constant 512)

  float* ws   = (float*)d_ws;
  float* coef = ws;                        // 1920 floats
  float* WhT  = coef + 2048;               // 512*128
  float* W2T  = WhT + (size_t)512 * 128;   // 128*128
  float* maxd = W2T + (size_t)128 * 128;   // 512

  hipLaunchKernelGGL(coef_k, dim3(1), dim3(512), 0, stream,
                     Wemb, bemb, Wi, W1, lb, coef);
  hipLaunchKernelGGL(transpose_k, dim3(640), dim3(128), 0, stream, Wh, W2, WhT, W2T);
  hipLaunchKernelGGL(decode_k, dim3(NBLK), dim3(1024), 0, stream,
                     outputs, WhT, Wh, W2T, av, coef, maxd);
  hipLaunchKernelGGL(reduce_k, dim3(1), dim3(512), 0, stream, maxd, (float*)d_out);
}